// Round 4
// baseline (207.830 us; speedup 1.0000x reference)
//
#include <hip/hip_runtime.h>
#include <cmath>

// RetinaNet focal + smooth-L1 loss, fully fused single kernel.
// B=4, C=80 fixed by reference; N, M from in_sizes.
#define GT_CAP 64           // max GT boxes stageable in LDS (actual M=16)

typedef float fvec4 __attribute__((ext_vector_type(4)));

__global__ __launch_bounds__(256) void retina_fused(
    const float* __restrict__ cls_heads,   // (B, N, 80)
    const float* __restrict__ reg_heads,   // (B, N, 4)
    const float* __restrict__ anchors,     // (B, N, 4) — broadcast across B
    const float* __restrict__ annots,      // (B, M, 5)
    float* __restrict__ ws,                // [0..3] cls, [4..7] reg, [8..11] pos, [12] counter
    float* __restrict__ out,               // out[0]=cls_loss, out[1]=reg_loss
    int N, int M, int B, int totBlocks)
{
    const int b  = blockIdx.y;
    const int n0 = blockIdx.x << 8;        // 256 anchors per block
    const int t  = threadIdx.x;

    __shared__ float s_ann[5 * GT_CAP];
    __shared__ float s_lab[256];
    __shared__ float s_red[12];

    const int mm = (M > GT_CAP) ? GT_CAP : M;
    for (int i = t; i < 5 * mm; i += 256)
        s_ann[i] = annots[(size_t)b * 5 * M + i];
    __syncthreads();

    // ---- phase 1: per-anchor assignment (label, targets, smooth-L1) ----
    float reg_acc = 0.0f;
    float pos_cnt = 0.0f;
    float label   = -1.0f;
    const int n = n0 + t;
    if (n < N) {
        // anchors are identical across batch (broadcast) — read plane 0 so the
        // 4.9 MB region is cache-served for b>0 instead of 4x HBM traffic.
        const float4 a = *(const float4*)(anchors + (size_t)n * 4);
        const bool inside = (a.x > 0.0f) && (a.y > 0.0f) &&
                            (a.z < 640.0f) && (a.w < 640.0f);
        if (inside) {
            const float area_a = (a.z - a.x) * (a.w - a.y);
            float best = -3.0e38f;
            int   bi   = 0;
            bool  any  = false;
            for (int m = 0; m < mm; ++m) {
                const float gx1 = s_ann[m*5+0], gy1 = s_ann[m*5+1];
                const float gx2 = s_ann[m*5+2], gy2 = s_ann[m*5+3];
                const float gc  = s_ann[m*5+4];
                float v = -1.0f;
                if (gc >= 0.0f) {
                    any = true;
                    const float iw = fmaxf(fminf(a.z, gx2) - fmaxf(a.x, gx1), 0.0f);
                    const float ih = fmaxf(fminf(a.w, gy2) - fmaxf(a.y, gy1), 0.0f);
                    const float inter = iw * ih;
                    v = inter / (area_a + (gx2 - gx1) * (gy2 - gy1) - inter);
                }
                if (v > best) { best = v; bi = m; }   // strict > == first-max (jnp.argmax)
            }
            if (any) {
                if (best < 0.4f)      label = 0.0f;
                else if (best > 0.5f) label = s_ann[bi*5+4] + 1.0f;
                // 0.4 <= best <= 0.5 stays -1 (ignore)
            }
            if (label > 0.0f) {
                pos_cnt = 1.0f;
                const float aw = a.z - a.x, ah = a.w - a.y;
                const float acx = a.x + 0.5f * aw, acy = a.y + 0.5f * ah;
                const float gw = fmaxf(s_ann[bi*5+2] - s_ann[bi*5+0], 1.0f);
                const float gh = fmaxf(s_ann[bi*5+3] - s_ann[bi*5+1], 1.0f);
                const float gcx = s_ann[bi*5+0] + 0.5f * gw;
                const float gcy = s_ann[bi*5+1] + 0.5f * gh;
                // targets / [0.1,0.1,0.2,0.2]
                const float tx = (gcx - acx) / aw * 10.0f;
                const float ty = (gcy - acy) / ah * 10.0f;
                const float tw = __logf(gw / aw) * 5.0f;
                const float th = __logf(gh / ah) * 5.0f;
                const float4 r = *(const float4*)(reg_heads + ((size_t)b * N + n) * 4);
                const float dx[4] = { fabsf(r.x - tx), fabsf(r.y - ty),
                                      fabsf(r.z - tw), fabsf(r.w - th) };
                #pragma unroll
                for (int j = 0; j < 4; ++j) {
                    const float x = dx[j];
                    // BETA = 1/9: 0.5*x*x/BETA = 4.5*x*x ; x - 0.5*BETA = x - 1/18
                    reg_acc += (x < (1.0f / 9.0f)) ? 4.5f * x * x
                                                   : x - (1.0f / 18.0f);
                }
            }
        }
    }
    s_lab[t] = label;

    // Block-wide early-out: border blocks have all labels == -1 (clustered),
    // skip the whole cls sweep (no loads, no math). Also serves as the barrier
    // making s_lab visible.
    const int anyValid = __syncthreads_or(label >= 0.0f ? 1 : 0);

    // ---- phase 2: focal loss, 256 anchors x 80 classes, coalesced float4 ----
    // Loads are UNCONDITIONAL and fully unrolled so all 20 dwordx4 issue
    // back-to-back (outstanding vmcnt pipelining); the math is predicated by
    // a mask multiply instead of a branch. This kernel is latency-bound, not
    // BW-bound (R3: 0.5 TB/s, VALUBusy 20%) — branch-gated loads serialized it.
    float cls_acc = 0.0f;
    if (anyValid) {
        const float* cls_base = cls_heads + ((size_t)b * N + n0) * 80;
        int a  = t / 20;            // anchor within block for k=0
        int c4 = t - a * 20;        // float4-chunk within the 80 classes
        #pragma unroll
        for (int k = 0; k < 20; ++k) {
            const fvec4 p4 = *(const fvec4*)(cls_base + 4 * t + 1024 * k);
            const float lab  = s_lab[a];
            const float mask = (lab >= 0.0f) ? 1.0f : 0.0f;
            const float pv[4] = { p4.x, p4.y, p4.z, p4.w };
            const float cb = (float)(c4 * 4 + 1);
            float local = 0.0f;
            #pragma unroll
            for (int j = 0; j < 4; ++j) {
                const float p = fminf(fmaxf(pv[j], 1.0e-4f), 1.0f - 1.0e-4f);
                const bool  is_pos = (lab == cb + (float)j);
                const float pt     = is_pos ? p : 1.0f - p;
                const float alpha  = is_pos ? 0.25f : 0.75f;
                const float om     = 1.0f - pt;
                local += alpha * om * om * (-__logf(pt));
            }
            cls_acc += mask * local;
            // e += 256 == 12*20 + 16  →  a += 12, c4 += 16, carry once
            a += 12; c4 += 16;
            if (c4 >= 20) { c4 -= 20; ++a; }
        }
    }

    // ---- block reduction: 3 values over 256 threads ----
    const int lane = t & 63, wid = t >> 6;
    #pragma unroll
    for (int off = 32; off > 0; off >>= 1) {
        cls_acc += __shfl_down(cls_acc, off, 64);
        reg_acc += __shfl_down(reg_acc, off, 64);
        pos_cnt += __shfl_down(pos_cnt, off, 64);
    }
    if (lane == 0) {
        s_red[wid]     = cls_acc;
        s_red[4 + wid] = reg_acc;
        s_red[8 + wid] = pos_cnt;
    }
    __syncthreads();

    if (t == 0) {
        const float c = s_red[0] + s_red[1] + s_red[2]  + s_red[3];
        const float r = s_red[4] + s_red[5] + s_red[6]  + s_red[7];
        const float p = s_red[8] + s_red[9] + s_red[10] + s_red[11];
        if (c != 0.0f) atomicAdd(&ws[b], c);
        if (r != 0.0f) atomicAdd(&ws[B + b], r);
        if (p != 0.0f) atomicAdd(&ws[2 * B + b], p);
        __threadfence();                         // sums visible before counter
        int* cnt = (int*)(ws + 3 * B);
        const int done = atomicAdd(cnt, 1);      // device-scope RMW
        if (done == totBlocks - 1) {
            // last block: finalize. Atomic RMW reads = coherent across XCDs.
            float cl = 0.0f, rl = 0.0f, nv = 0.0f;
            for (int bb = 0; bb < B; ++bb) {
                const float pos = atomicAdd(&ws[2 * B + bb], 0.0f);
                const float cs  = atomicAdd(&ws[bb],         0.0f);
                const float rs  = atomicAdd(&ws[B + bb],     0.0f);
                if (pos > 0.0f) {
                    cl += cs / fmaxf(pos, 1.0f);
                    rl += rs / fmaxf(4.0f * pos, 1.0f);
                    nv += 1.0f;
                }
            }
            const float nrm = fmaxf(nv, 1.0f);
            out[0] = cl / nrm;
            out[1] = rl / nrm;
        }
    }
}

extern "C" void kernel_launch(void* const* d_in, const int* in_sizes, int n_in,
                              void* d_out, int out_size, void* d_ws, size_t ws_size,
                              hipStream_t stream) {
    const float* cls = (const float*)d_in[0];
    const float* reg = (const float*)d_in[1];
    const float* anc = (const float*)d_in[2];
    const float* ann = (const float*)d_in[3];

    const int B = 4;                          // per reference setup
    const int N = in_sizes[1] / (4 * B);      // 76725
    const int M = in_sizes[3] / (5 * B);      // 16
    float* ws = (float*)d_ws;

    // zero: 12 partial sums + completion counter
    (void)hipMemsetAsync(d_ws, 0, 16 * sizeof(float), stream);

    dim3 grid((N + 255) / 256, B);
    const int totBlocks = grid.x * grid.y;
    retina_fused<<<grid, 256, 0, stream>>>(cls, reg, anc, ann, ws,
                                           (float*)d_out, N, M, B, totBlocks);
}

// Round 5
// 164.631 us; speedup vs baseline: 1.2624x; 1.2624x over previous
//
#include <hip/hip_runtime.h>
#include <cmath>

// RetinaNet focal + smooth-L1 loss. Split structure (main + finalize):
// in-kernel device fences/atomic-counter finalize measured +25-30us vs
// kernel-boundary coherence (R3/R4 post-mortem). B=4, C=80 fixed.
#define GT_CAP 64
#define PF 4                 // software-pipeline depth (outstanding loads/wave)

typedef float fvec4 __attribute__((ext_vector_type(4)));

__global__ __launch_bounds__(256) void retina_main(
    const float* __restrict__ cls_heads,   // (B, N, 80)
    const float* __restrict__ reg_heads,   // (B, N, 4)
    const float* __restrict__ anchors,     // (B, N, 4) — broadcast across B
    const float* __restrict__ annots,      // (B, M, 5)
    float* __restrict__ ws,                // [B] cls, [B] reg, [B] pos
    int N, int M, int B)
{
    const int b  = blockIdx.y;
    const int n0 = blockIdx.x << 8;
    const int t  = threadIdx.x;

    __shared__ float s_ann[5 * GT_CAP];
    __shared__ float s_lab[256];
    __shared__ float s_red[12];

    const int mm = (M > GT_CAP) ? GT_CAP : M;
    for (int i = t; i < 5 * mm; i += 256)
        s_ann[i] = annots[(size_t)b * 5 * M + i];
    __syncthreads();

    // ---- phase 1: per-anchor assignment ----
    float reg_acc = 0.0f;
    float pos_cnt = 0.0f;
    float label   = -1.0f;
    const int n = n0 + t;
    if (n < N) {
        // anchors identical across batch: read plane 0 (cache-served for b>0)
        const float4 a = *(const float4*)(anchors + (size_t)n * 4);
        const bool inside = (a.x > 0.0f) && (a.y > 0.0f) &&
                            (a.z < 640.0f) && (a.w < 640.0f);
        if (inside) {
            const float area_a = (a.z - a.x) * (a.w - a.y);
            float best = -3.0e38f;
            int   bi   = 0;
            bool  any  = false;
            for (int m = 0; m < mm; ++m) {
                const float gx1 = s_ann[m*5+0], gy1 = s_ann[m*5+1];
                const float gx2 = s_ann[m*5+2], gy2 = s_ann[m*5+3];
                const float gc  = s_ann[m*5+4];
                float v = -1.0f;
                if (gc >= 0.0f) {
                    any = true;
                    const float iw = fmaxf(fminf(a.z, gx2) - fmaxf(a.x, gx1), 0.0f);
                    const float ih = fmaxf(fminf(a.w, gy2) - fmaxf(a.y, gy1), 0.0f);
                    const float inter = iw * ih;
                    v = inter / (area_a + (gx2 - gx1) * (gy2 - gy1) - inter);
                }
                if (v > best) { best = v; bi = m; }   // first-max == jnp.argmax
            }
            if (any) {
                if (best < 0.4f)      label = 0.0f;
                else if (best > 0.5f) label = s_ann[bi*5+4] + 1.0f;
            }
            if (label > 0.0f) {
                pos_cnt = 1.0f;
                const float aw = a.z - a.x, ah = a.w - a.y;
                const float acx = a.x + 0.5f * aw, acy = a.y + 0.5f * ah;
                const float gw = fmaxf(s_ann[bi*5+2] - s_ann[bi*5+0], 1.0f);
                const float gh = fmaxf(s_ann[bi*5+3] - s_ann[bi*5+1], 1.0f);
                const float gcx = s_ann[bi*5+0] + 0.5f * gw;
                const float gcy = s_ann[bi*5+1] + 0.5f * gh;
                const float tx = (gcx - acx) / aw * 10.0f;
                const float ty = (gcy - acy) / ah * 10.0f;
                const float tw = __logf(gw / aw) * 5.0f;
                const float th = __logf(gh / ah) * 5.0f;
                const float4 r = *(const float4*)(reg_heads + ((size_t)b * N + n) * 4);
                const float dx[4] = { fabsf(r.x - tx), fabsf(r.y - ty),
                                      fabsf(r.z - tw), fabsf(r.w - th) };
                #pragma unroll
                for (int j = 0; j < 4; ++j) {
                    const float x = dx[j];
                    reg_acc += (x < (1.0f / 9.0f)) ? 4.5f * x * x
                                                   : x - (1.0f / 18.0f);
                }
            }
        }
    }
    s_lab[t] = label;
    const int anyValid = __syncthreads_or(label >= 0.0f ? 1 : 0);

    // ---- phase 2: focal loss, software-pipelined depth-PF conditional loads ----
    // R4 lesson: compiler won't batch loads itself (VGPR=28, serial
    // load->waitcnt->use). Manual ring buffer gives PF outstanding loads/wave.
    // Loads stay exec-mask-conditional (lab<0 lanes issue nothing — free BW skip).
    float cls_acc = 0.0f;
    if (anyValid) {
        const float* cls_base = cls_heads + ((size_t)b * N + n0) * 80;
        int ap = t / 20, c4p = t - ap * 20;   // prefetch iterator
        int c4c = c4p;                        // process iterator (chunk only)
        float labb[PF];
        fvec4 pb[PF];
        #pragma unroll
        for (int k = 0; k < PF; ++k) {
            const float lab = s_lab[ap];
            fvec4 v = {0.5f, 0.5f, 0.5f, 0.5f};
            if (lab >= 0.0f) v = *(const fvec4*)(cls_base + 4 * t + 1024 * k);
            labb[k] = lab; pb[k] = v;
            ap += 12; c4p += 16; if (c4p >= 20) { c4p -= 20; ++ap; }
        }
        #pragma unroll
        for (int k = 0; k < 20; ++k) {
            const float lab = labb[k % PF];
            const fvec4 v   = pb[k % PF];
            if (k + PF < 20) {                 // refill slot with iter k+PF
                const float labn = s_lab[ap];
                fvec4 vn = {0.5f, 0.5f, 0.5f, 0.5f};
                if (labn >= 0.0f)
                    vn = *(const fvec4*)(cls_base + 4 * t + 1024 * (k + PF));
                labb[k % PF] = labn; pb[k % PF] = vn;
                ap += 12; c4p += 16; if (c4p >= 20) { c4p -= 20; ++ap; }
            }
            const float mask = (lab >= 0.0f) ? 1.0f : 0.0f;
            const float pv[4] = { v.x, v.y, v.z, v.w };
            const float cb = (float)(c4c * 4 + 1);
            float local = 0.0f;
            #pragma unroll
            for (int j = 0; j < 4; ++j) {
                const float p = fminf(fmaxf(pv[j], 1.0e-4f), 1.0f - 1.0e-4f);
                const bool  is_pos = (lab == cb + (float)j);
                const float pt     = is_pos ? p : 1.0f - p;
                const float alpha  = is_pos ? 0.25f : 0.75f;
                const float om     = 1.0f - pt;
                local += alpha * om * om * (-__logf(pt));
            }
            cls_acc += mask * local;
            c4c += 16; if (c4c >= 20) c4c -= 20;
        }
    }

    // ---- block reduction ----
    const int lane = t & 63, wid = t >> 6;
    #pragma unroll
    for (int off = 32; off > 0; off >>= 1) {
        cls_acc += __shfl_down(cls_acc, off, 64);
        reg_acc += __shfl_down(reg_acc, off, 64);
        pos_cnt += __shfl_down(pos_cnt, off, 64);
    }
    if (lane == 0) {
        s_red[wid]     = cls_acc;
        s_red[4 + wid] = reg_acc;
        s_red[8 + wid] = pos_cnt;
    }
    __syncthreads();
    if (t == 0) {
        const float c = s_red[0] + s_red[1] + s_red[2]  + s_red[3];
        const float r = s_red[4] + s_red[5] + s_red[6]  + s_red[7];
        const float p = s_red[8] + s_red[9] + s_red[10] + s_red[11];
        if (c != 0.0f) atomicAdd(&ws[b], c);
        if (r != 0.0f) atomicAdd(&ws[B + b], r);
        if (p != 0.0f) atomicAdd(&ws[2 * B + b], p);
    }
}

__global__ void retina_final(const float* __restrict__ ws,
                             float* __restrict__ out, int B)
{
    if (threadIdx.x == 0 && blockIdx.x == 0) {
        float cl = 0.0f, rl = 0.0f, nv = 0.0f;
        for (int b = 0; b < B; ++b) {
            const float pos = ws[2 * B + b];
            if (pos > 0.0f) {
                cl += ws[b]     / fmaxf(pos, 1.0f);
                rl += ws[B + b] / fmaxf(4.0f * pos, 1.0f);
                nv += 1.0f;
            }
        }
        const float n = fmaxf(nv, 1.0f);
        out[0] = cl / n;
        out[1] = rl / n;
    }
}

extern "C" void kernel_launch(void* const* d_in, const int* in_sizes, int n_in,
                              void* d_out, int out_size, void* d_ws, size_t ws_size,
                              hipStream_t stream) {
    const float* cls = (const float*)d_in[0];
    const float* reg = (const float*)d_in[1];
    const float* anc = (const float*)d_in[2];
    const float* ann = (const float*)d_in[3];

    const int B = 4;
    const int N = in_sizes[1] / (4 * B);      // 76725
    const int M = in_sizes[3] / (5 * B);      // 16
    float* ws = (float*)d_ws;

    (void)hipMemsetAsync(d_ws, 0, 12 * sizeof(float), stream);

    dim3 grid((N + 255) / 256, B);
    retina_main<<<grid, 256, 0, stream>>>(cls, reg, anc, ann, ws, N, M, B);
    retina_final<<<1, 64, 0, stream>>>(ws, (float*)d_out, B);
}